// Round 2
// baseline (1150.996 us; speedup 1.0000x reference)
//
#include <hip/hip_runtime.h>
#include <math.h>

// Problem constants (fixed by reference)
constexpr int Bc   = 8;
constexpr int Nc   = 512;
constexpr int Dc   = 512;
constexpr int HHc  = 8;     // half the heads
constexpr int DHc  = 32;
constexpr int DEGc = 16;
constexpr int Ec   = Bc * Nc * DEGc;          // 65536 edges
constexpr float LN2   = 0.69314718055994530942f;
constexpr float SCALE = 0.17677669529663688110f;  // 1/sqrt(32)

typedef unsigned short ushort_t;
typedef __attribute__((ext_vector_type(8))) short short8;
typedef __attribute__((ext_vector_type(4))) float f32x4;

__device__ __forceinline__ float splus_m_ln2(float x) {
    float ax = fabsf(x);
    return fmaxf(x, 0.0f) + log1pf(expf(-ax)) - LN2;
}

__device__ __forceinline__ ushort_t f2bf(float x) {
    union { float f; unsigned int u; } v; v.f = x;
    unsigned int r = (v.u + 0x7fffu + ((v.u >> 16) & 1u)) >> 16;   // RNE
    return (ushort_t)r;
}
__device__ __forceinline__ float bf2f(ushort_t x) {
    union { unsigned int u; float f; } v; v.u = ((unsigned int)x) << 16;
    return v.f;
}

__device__ __forceinline__ void gload16(const ushort_t* g, ushort_t* l) {
    __builtin_amdgcn_global_load_lds(
        (const __attribute__((address_space(1))) void*)g,
        (__attribute__((address_space(3))) void*)l, 16, 0, 0);
}

// ---------------------------------------------------------------------------
// bf16 MFMA GEMM (m97 structure): C[M,NOUT] = act(A[M,K] @ Bt^T + bias)
// A: bf16 [M][K] row-major (or GATHER: rows = concat(out[b,i], out[b,j]))
// Bt: bf16 [NOUT][K] (pre-transposed weight)
// OUTMODE: 0 = fp32 out, 1 = bf16 out, 2 = fp32 out + bf16 copy to Cout2
// 128x128 block tile, BK=32, 256 threads = 4 waves in 2x2, 4x4 MFMA frags/wave.
// LDS layout [row][32] bf16 unpadded — required by global_load_lds lane order.
// ---------------------------------------------------------------------------
template<int ACT, int GATHER, int OUTMODE>
__global__ __launch_bounds__(256) void gemm_mfma(
    const ushort_t* __restrict__ A, const ushort_t* __restrict__ Bt,
    const float* __restrict__ bias, void* __restrict__ Cout,
    ushort_t* __restrict__ Cout2,
    int K, int NOUT,
    const int* __restrict__ pb, const int* __restrict__ pi,
    const int* __restrict__ pj)
{
    __shared__ ushort_t As[128 * 32];
    __shared__ ushort_t Bs[128 * 32];

    const int t    = threadIdx.x;
    const int lane = t & 63;
    const int w    = t >> 6;
    const int wy   = w >> 1, wx = w & 1;
    const int rowBase = blockIdx.y * 128;
    const int colBase = blockIdx.x * 128;

    // staging: thread t loads row (r*64 + t>>2), k-chunk (t&3)*8
    const int sm0 = t >> 2;
    const int kch = (t & 3) * 8;

    const ushort_t *a0i, *a0j = nullptr, *a1i, *a1j = nullptr;
    if (GATHER) {
        const int e0 = rowBase + sm0, e1 = rowBase + 64 + sm0;
        a0i = A + ((size_t)(pb[e0] * Nc + pi[e0])) * Dc;
        a0j = A + ((size_t)(pb[e0] * Nc + pj[e0])) * Dc;
        a1i = A + ((size_t)(pb[e1] * Nc + pi[e1])) * Dc;
        a1j = A + ((size_t)(pb[e1] * Nc + pj[e1])) * Dc;
    } else {
        a0i = A + (size_t)(rowBase + sm0) * K;
        a1i = A + (size_t)(rowBase + 64 + sm0) * K;
    }
    const ushort_t* b0 = Bt + (size_t)(colBase + sm0) * K;
    const ushort_t* b1 = Bt + (size_t)(colBase + 64 + sm0) * K;

    // wave-uniform LDS staging bases (in ushort elements; *16B per lane)
    ushort_t* asd0 = As + (size_t)(w * 64) * 8;
    ushort_t* asd1 = As + (size_t)(256 + w * 64) * 8;
    ushort_t* bsd0 = Bs + (size_t)(w * 64) * 8;
    ushort_t* bsd1 = Bs + (size_t)(256 + w * 64) * 8;

    f32x4 acc[4][4];
    const f32x4 fz = {0.f, 0.f, 0.f, 0.f};
    #pragma unroll
    for (int i = 0; i < 4; ++i)
        #pragma unroll
        for (int j = 0; j < 4; ++j) acc[i][j] = fz;

    const int c16 = lane & 15;
    const int q16 = lane >> 4;

    const int nkb = K >> 5;
    for (int kb = 0; kb < nkb; ++kb) {
        const int k0 = kb << 5;
        __syncthreads();   // previous iteration's LDS reads complete
        const ushort_t *pa0, *pa1;
        if (GATHER) {
            const bool first = (k0 < Dc);
            const int kk = first ? k0 : (k0 - Dc);
            pa0 = (first ? a0i : a0j) + kk + kch;
            pa1 = (first ? a1i : a1j) + kk + kch;
        } else {
            pa0 = a0i + k0 + kch;
            pa1 = a1i + k0 + kch;
        }
        gload16(pa0, asd0);
        gload16(pa1, asd1);
        gload16(b0 + k0 + kch, bsd0);
        gload16(b1 + k0 + kch, bsd1);
        __syncthreads();   // staging visible (vmcnt drained before barrier)

        short8 af[4], bf[4];
        #pragma unroll
        for (int i = 0; i < 4; ++i)
            af[i] = *(const short8*)&As[(size_t)((wy * 64 + i * 16 + c16) * 32 + q16 * 8)];
        #pragma unroll
        for (int j = 0; j < 4; ++j)
            bf[j] = *(const short8*)&Bs[(size_t)((wx * 64 + j * 16 + c16) * 32 + q16 * 8)];
        #pragma unroll
        for (int i = 0; i < 4; ++i)
            #pragma unroll
            for (int j = 0; j < 4; ++j)
                acc[i][j] = __builtin_amdgcn_mfma_f32_16x16x32_bf16(af[i], bf[j], acc[i][j], 0, 0, 0);
    }

    // Epilogue: C/D layout col=lane&15, row=(lane>>4)*4+reg  [m89-verified]
    #pragma unroll
    for (int j = 0; j < 4; ++j) {
        const int col = colBase + wx * 64 + j * 16 + c16;
        const float bv = bias[col];
        #pragma unroll
        for (int i = 0; i < 4; ++i) {
            const int row0 = rowBase + wy * 64 + i * 16 + q16 * 4;
            #pragma unroll
            for (int r = 0; r < 4; ++r) {
                float v = acc[i][j][r] + bv;
                if (ACT) v = splus_m_ln2(v);
                const size_t idx = (size_t)(row0 + r) * NOUT + col;
                if (OUTMODE == 1) {
                    ((ushort_t*)Cout)[idx] = f2bf(v);
                } else {
                    ((float*)Cout)[idx] = v;
                    if (OUTMODE == 2) Cout2[idx] = f2bf(v);
                }
            }
        }
    }
}

// ---------------------------------------------------------------------------
// Conversion helpers
// ---------------------------------------------------------------------------
__global__ __launch_bounds__(256) void cvt_f32_bf16(
    const float* __restrict__ src, ushort_t* __restrict__ dst)
{
    const int i = blockIdx.x * 256 + threadIdx.x;
    float4 v = ((const float4*)src)[i];
    ushort4 o;
    o.x = f2bf(v.x); o.y = f2bf(v.y); o.z = f2bf(v.z); o.w = f2bf(v.w);
    ((ushort4*)dst)[i] = o;
}

// Wt[n][k] = bf16(W[k][n]); block (32,8), one 32x32 tile per block
__global__ void transpose_cvt(const float* __restrict__ W, ushort_t* __restrict__ Wt,
                              int K, int NOUT)
{
    __shared__ float tile[32][33];
    const int k0 = blockIdx.x * 32, n0 = blockIdx.y * 32;
    #pragma unroll
    for (int r = 0; r < 4; ++r)
        tile[threadIdx.y + r * 8][threadIdx.x] =
            W[(size_t)(k0 + threadIdx.y + r * 8) * NOUT + n0 + threadIdx.x];
    __syncthreads();
    #pragma unroll
    for (int r = 0; r < 4; ++r)
        Wt[(size_t)(n0 + threadIdx.y + r * 8) * K + k0 + threadIdx.x] =
            f2bf(tile[threadIdx.x][threadIdx.y + r * 8]);
}

// ---------------------------------------------------------------------------
// Global attention (fp32): one wave per (b, h<HH, qi)
// ctx layout: ctx[b,n, h*64+0:32]=global head h ; [h*64+32:64]=local head h
// ---------------------------------------------------------------------------
__global__ __launch_bounds__(256) void global_attn(
    const float* __restrict__ qp, const float* __restrict__ kp,
    const float* __restrict__ vp, float* __restrict__ ctx,
    float* __restrict__ top)
{
    __shared__ float wsm[4][512];
    __shared__ float qs[4][32];
    const int wv   = threadIdx.x >> 6;
    const int lane = threadIdx.x & 63;
    const int row  = blockIdx.x * 4 + wv;
    const int qi   = row & (Nc - 1);
    const int bh   = row >> 9;
    const int h    = bh & (HHc - 1);
    const int b    = bh >> 3;

    const size_t qoff = ((size_t)(b * Nc + qi)) * Dc + h * DHc;
    if (lane < DHc) qs[wv][lane] = qp[qoff + lane];
    __syncthreads();

    float qreg[32];
    #pragma unroll
    for (int d4 = 0; d4 < 8; ++d4) {
        float4 v = *(const float4*)&qs[wv][d4 << 2];
        qreg[(d4 << 2) + 0] = v.x; qreg[(d4 << 2) + 1] = v.y;
        qreg[(d4 << 2) + 2] = v.z; qreg[(d4 << 2) + 3] = v.w;
    }

    float sc[8];
    #pragma unroll
    for (int r = 0; r < 8; ++r) {
        const int j = (r << 6) + lane;
        const float* krow = kp + ((size_t)(b * Nc + j)) * Dc + h * DHc;
        float s = 0.f;
        #pragma unroll
        for (int d4 = 0; d4 < 8; ++d4) {
            float4 kv = *(const float4*)&krow[d4 << 2];
            s += qreg[(d4 << 2) + 0] * kv.x + qreg[(d4 << 2) + 1] * kv.y
               + qreg[(d4 << 2) + 2] * kv.z + qreg[(d4 << 2) + 3] * kv.w;
        }
        sc[r] = s * SCALE;
    }

    if (h == 0) {
        float* trow = top + ((size_t)(b * Nc + qi)) * Nc;
        #pragma unroll
        for (int r = 0; r < 8; ++r) trow[(r << 6) + lane] = sc[r];
    }

    float m = sc[0];
    #pragma unroll
    for (int r = 1; r < 8; ++r) m = fmaxf(m, sc[r]);
    #pragma unroll
    for (int off = 32; off > 0; off >>= 1) m = fmaxf(m, __shfl_xor(m, off, 64));
    float l = 0.f, wgt[8];
    #pragma unroll
    for (int r = 0; r < 8; ++r) { wgt[r] = expf(sc[r] - m); l += wgt[r]; }
    #pragma unroll
    for (int off = 32; off > 0; off >>= 1) l += __shfl_xor(l, off, 64);
    const float inv = 1.0f / l;
    #pragma unroll
    for (int r = 0; r < 8; ++r) wsm[wv][(r << 6) + lane] = wgt[r] * inv;
    __syncthreads();

    // PV: 4 independent accumulator chains (break serial FMA dependency)
    const int d  = lane & 31;
    const int s2 = lane >> 5;
    const float* vcol = vp + ((size_t)(b * Nc)) * Dc + h * DHc + d;
    const int j0 = s2 << 8;
    float a0 = 0.f, a1 = 0.f, a2 = 0.f, a3 = 0.f;
    #pragma unroll 2
    for (int j = 0; j < 256; j += 4) {
        a0 += wsm[wv][j0 + j + 0] * vcol[(size_t)(j0 + j + 0) * Dc];
        a1 += wsm[wv][j0 + j + 1] * vcol[(size_t)(j0 + j + 1) * Dc];
        a2 += wsm[wv][j0 + j + 2] * vcol[(size_t)(j0 + j + 2) * Dc];
        a3 += wsm[wv][j0 + j + 3] * vcol[(size_t)(j0 + j + 3) * Dc];
    }
    float a = (a0 + a1) + (a2 + a3);
    a += __shfl_xor(a, 32, 64);
    if (lane < 32)
        ctx[((size_t)(b * Nc + qi)) * Dc + (h << 6) + d] = a;
}

// ---------------------------------------------------------------------------
// Local attention (ef2 bf16)
// ---------------------------------------------------------------------------
__global__ __launch_bounds__(256) void local_scores(
    const float* __restrict__ qp, const float* __restrict__ kp,
    const ushort_t* __restrict__ ef2,
    const int* __restrict__ pb, const int* __restrict__ pi,
    const int* __restrict__ pj, float* __restrict__ sl)
{
    const int gid = blockIdx.x * 256 + threadIdx.x;   // e*8 + h
    const int h = gid & 7;
    const int e = gid >> 3;
    const int b = pb[e], i = pi[e], j = pj[e];
    const float* qrow = qp  + ((size_t)(b * Nc + i)) * Dc + (HHc + h) * DHc;
    const float* krow = kp  + ((size_t)(b * Nc + j)) * Dc + (HHc + h) * DHc;
    const ushort_t* erow = ef2 + (size_t)e * 256 + h * DHc;
    float s = 0.f;
    #pragma unroll
    for (int d4 = 0; d4 < 8; ++d4) {
        float4 qv = *(const float4*)&qrow[d4 << 2];
        float4 kv = *(const float4*)&krow[d4 << 2];
        ushort4 ev = *(const ushort4*)&erow[d4 << 2];
        s += qv.x * kv.x * bf2f(ev.x) + qv.y * kv.y * bf2f(ev.y)
           + qv.z * kv.z * bf2f(ev.z) + qv.w * kv.w * bf2f(ev.w);
    }
    sl[gid] = s * SCALE;
}

__global__ __launch_bounds__(256) void local_softmax(float* __restrict__ sl)
{
    const int gid = blockIdx.x * 256 + threadIdx.x;   // bi*8 + h
    const int h  = gid & 7;
    const int bi = gid >> 3;
    float s[DEGc];
    float m = -1e30f;
    #pragma unroll
    for (int tt = 0; tt < DEGc; ++tt) {
        s[tt] = sl[(size_t)(bi * DEGc + tt) * 8 + h];
        m = fmaxf(m, s[tt]);
    }
    float l = 0.f;
    #pragma unroll
    for (int tt = 0; tt < DEGc; ++tt) { s[tt] = expf(s[tt] - m); l += s[tt]; }
    const float inv = 1.0f / l;
    #pragma unroll
    for (int tt = 0; tt < DEGc; ++tt)
        sl[(size_t)(bi * DEGc + tt) * 8 + h] = s[tt] * inv;
}

__global__ __launch_bounds__(256) void local_ctx_kernel(
    const float* __restrict__ vp, const float* __restrict__ sl,
    const int* __restrict__ pj, float* __restrict__ ctx)
{
    const int bi = blockIdx.x;            // b*N + i
    const int t  = threadIdx.x;
    const int d  = t & 31;
    const int h  = t >> 5;
    __shared__ float a_s[DEGc][8];
    __shared__ int   jrow[DEGc];
    const int b = bi >> 9;
    if (t < DEGc) jrow[t] = pj[bi * DEGc + t];
    if (t < DEGc * 8) a_s[t >> 3][t & 7] = sl[(size_t)bi * (DEGc * 8) + t];
    __syncthreads();
    float acc = 0.f;
    #pragma unroll
    for (int tt = 0; tt < DEGc; ++tt) {
        const int j = jrow[tt];
        acc += a_s[tt][h] * vp[((size_t)(b * Nc + j)) * Dc + (HHc + h) * DHc + d];
    }
    ctx[(size_t)bi * Dc + (h << 6) + 32 + d] = acc;
}

// ---------------------------------------------------------------------------
extern "C" void kernel_launch(void* const* d_in, const int* in_sizes, int n_in,
                              void* d_out, int out_size, void* d_ws, size_t ws_size,
                              hipStream_t stream) {
    const float* key   = (const float*)d_in[0];
    const float* value = (const float*)d_in[1];
    const float* query = (const float*)d_in[2];
    const float* edge_feature = (const float*)d_in[4];
    const int* pb = (const int*)d_in[5];
    const int* pi = (const int*)d_in[6];
    const int* pj = (const int*)d_in[7];
    const float* Wq = (const float*)d_in[8];  const float* bq = (const float*)d_in[9];
    const float* Wk = (const float*)d_in[10]; const float* bk = (const float*)d_in[11];
    const float* Wv = (const float*)d_in[12]; const float* bv = (const float*)d_in[13];
    const float* Wo = (const float*)d_in[14]; const float* bo = (const float*)d_in[15];
    const float* We1 = (const float*)d_in[16]; const float* be1 = (const float*)d_in[17];
    const float* We2 = (const float*)d_in[18]; const float* be2 = (const float*)d_in[19];
    const float* Wu1 = (const float*)d_in[20]; const float* bu1 = (const float*)d_in[21];
    const float* Wu2 = (const float*)d_in[22]; const float* bu2 = (const float*)d_in[23];

    float* out  = (float*)d_out;          // (B,N,D)
    float* top  = out + 2097152;          // (B,N,N)
    float* eupd = out + 4194304;          // (E,D)

    float* qp  = (float*)d_ws;            // 2097152 f
    float* kp  = qp + 2097152;
    float* vp  = kp + 2097152;
    float* ctx = vp + 2097152;
    float* sl  = ctx + 2097152;           // 524288 f
    ushort_t* ef2b  = (ushort_t*)(sl + 524288);   // E*256
    ushort_t* efb   = ef2b + 16777216;            // E*512
    ushort_t* hidb  = efb + 33554432;             // E*512
    ushort_t* outb  = hidb + 33554432;            // 2097152
    ushort_t* wt_e1 = outb + 2097152;             // 512*512
    ushort_t* wt_e2 = wt_e1 + 262144;             // 256*512
    ushort_t* wt_u1 = wt_e2 + 131072;             // 512*1024
    ushort_t* wt_u2 = wt_u1 + 524288;             // 512*512

    // Aliased into efb's region — efb is dead after the first edge-MLP GEMM,
    // and the edge path is launched FIRST (stream-serialized), so no overlap.
    ushort_t* wt_q = efb;                 // 262144
    ushort_t* wt_k = wt_q + 262144;
    ushort_t* wt_v = wt_k + 262144;
    ushort_t* wt_o = wt_v + 262144;
    ushort_t* qb   = wt_o + 262144;       // 2097152
    ushort_t* kb   = qb + 2097152;
    ushort_t* vb   = kb + 2097152;
    ushort_t* ctxb = vb + 2097152;        // ends at efb+9437184 < 33554432 ok

    dim3 blk(256);
    dim3 tblk(32, 8);

    // ---- Edge path first (frees efb for aliasing) ----
    transpose_cvt<<<dim3(16, 16), tblk, 0, stream>>>(We1, wt_e1, 512, 512);
    transpose_cvt<<<dim3(16, 8),  tblk, 0, stream>>>(We2, wt_e2, 512, 256);
    transpose_cvt<<<dim3(32, 16), tblk, 0, stream>>>(Wu1, wt_u1, 1024, 512);
    transpose_cvt<<<dim3(16, 16), tblk, 0, stream>>>(Wu2, wt_u2, 512, 512);
    cvt_f32_bf16<<<32768, blk, 0, stream>>>(edge_feature, efb);

    // Edge MLP (bf16 MFMA): hid = act(ef @ We1 + be1); ef2 = hid @ We2 + be2
    gemm_mfma<1, 0, 1><<<dim3(4, 512), blk, 0, stream>>>(efb, wt_e1, be1, hidb, nullptr, 512, 512, nullptr, nullptr, nullptr);
    gemm_mfma<0, 0, 1><<<dim3(2, 512), blk, 0, stream>>>(hidb, wt_e2, be2, ef2b, nullptr, 512, 256, nullptr, nullptr, nullptr);
    // efb dead from here on.

    // ---- QKV projections on the matrix pipe (was fp32 gemm64) ----
    transpose_cvt<<<dim3(16, 16), tblk, 0, stream>>>(Wq, wt_q, 512, 512);
    transpose_cvt<<<dim3(16, 16), tblk, 0, stream>>>(Wk, wt_k, 512, 512);
    transpose_cvt<<<dim3(16, 16), tblk, 0, stream>>>(Wv, wt_v, 512, 512);
    transpose_cvt<<<dim3(16, 16), tblk, 0, stream>>>(Wo, wt_o, 512, 512);
    cvt_f32_bf16<<<2048, blk, 0, stream>>>(query, qb);
    cvt_f32_bf16<<<2048, blk, 0, stream>>>(key,   kb);
    cvt_f32_bf16<<<2048, blk, 0, stream>>>(value, vb);

    gemm_mfma<0, 0, 0><<<dim3(4, 32), blk, 0, stream>>>(qb, wt_q, bq, qp, nullptr, 512, 512, nullptr, nullptr, nullptr);
    gemm_mfma<0, 0, 0><<<dim3(4, 32), blk, 0, stream>>>(kb, wt_k, bk, kp, nullptr, 512, 512, nullptr, nullptr, nullptr);
    gemm_mfma<0, 0, 0><<<dim3(4, 32), blk, 0, stream>>>(vb, wt_v, bv, vp, nullptr, 512, 512, nullptr, nullptr, nullptr);

    // ---- Attention ----
    global_attn<<<8192, blk, 0, stream>>>(qp, kp, vp, ctx, top);
    local_scores<<<2048, blk, 0, stream>>>(qp, kp, ef2b, pb, pi, pj, sl);
    local_softmax<<<128, blk, 0, stream>>>(sl);
    local_ctx_kernel<<<4096, blk, 0, stream>>>(vp, sl, pj, ctx);

    // ---- Output projection (bf16 MFMA, writes fp32 out + bf16 outb) ----
    cvt_f32_bf16<<<2048, blk, 0, stream>>>(ctx, ctxb);
    gemm_mfma<0, 0, 2><<<dim3(4, 32), blk, 0, stream>>>(ctxb, wt_o, bo, out, outb, 512, 512, nullptr, nullptr, nullptr);

    // ---- Edge update MLP (bf16 MFMA, A gathered from outb, K=1024) ----
    gemm_mfma<1, 1, 1><<<dim3(4, 512), blk, 0, stream>>>(outb, wt_u1, bu1, hidb, nullptr, 1024, 512, pb, pi, pj);
    gemm_mfma<0, 0, 0><<<dim3(4, 512), blk, 0, stream>>>(hidb, wt_u2, bu2, eupd, nullptr, 512, 512, nullptr, nullptr, nullptr);
}

// Round 3
// 886.757 us; speedup vs baseline: 1.2980x; 1.2980x over previous
//
#include <hip/hip_runtime.h>
#include <math.h>

// Problem constants (fixed by reference)
constexpr int Bc   = 8;
constexpr int Nc   = 512;
constexpr int Dc   = 512;
constexpr int HHc  = 8;     // half the heads
constexpr int DHc  = 32;
constexpr int DEGc = 16;
constexpr int Ec   = Bc * Nc * DEGc;          // 65536 edges
constexpr float LN2   = 0.69314718055994530942f;
constexpr float SCALE = 0.17677669529663688110f;  // 1/sqrt(32)

typedef unsigned short ushort_t;
typedef __attribute__((ext_vector_type(8))) short short8;
typedef __attribute__((ext_vector_type(4))) float f32x4;

__device__ __forceinline__ float splus_m_ln2(float x) {
    float ax = fabsf(x);
    return fmaxf(x, 0.0f) + log1pf(expf(-ax)) - LN2;
}

__device__ __forceinline__ ushort_t f2bf(float x) {
    union { float f; unsigned int u; } v; v.f = x;
    unsigned int r = (v.u + 0x7fffu + ((v.u >> 16) & 1u)) >> 16;   // RNE
    return (ushort_t)r;
}
__device__ __forceinline__ float bf2f(ushort_t x) {
    union { unsigned int u; float f; } v; v.u = ((unsigned int)x) << 16;
    return v.f;
}

__device__ __forceinline__ void gload16(const ushort_t* g, ushort_t* l) {
    __builtin_amdgcn_global_load_lds(
        (const __attribute__((address_space(1))) void*)g,
        (__attribute__((address_space(3))) void*)l, 16, 0, 0);
}

// ---------------------------------------------------------------------------
// bf16 MFMA GEMM (m97 structure): C[M,NOUT] = act(A[M,K] @ Bt^T + bias)
// A: bf16 [M][K] row-major (or GATHER: rows = concat(out[b,i], out[b,j]))
// Bt: bf16 [NOUT][K] (pre-transposed weight)
// OUTMODE: 0 = fp32 out, 1 = bf16 out, 2 = fp32 out + bf16 copy to Cout2
// 128x128 block tile, BK=32, 256 threads = 4 waves in 2x2, 4x4 MFMA frags/wave.
// LDS layout [row][32] bf16 unpadded — required by global_load_lds lane order.
// ---------------------------------------------------------------------------
template<int ACT, int GATHER, int OUTMODE>
__global__ __launch_bounds__(256) void gemm_mfma(
    const ushort_t* __restrict__ A, const ushort_t* __restrict__ Bt,
    const float* __restrict__ bias, void* __restrict__ Cout,
    ushort_t* __restrict__ Cout2,
    int K, int NOUT,
    const int* __restrict__ pb, const int* __restrict__ pi,
    const int* __restrict__ pj)
{
    __shared__ ushort_t As[128 * 32];
    __shared__ ushort_t Bs[128 * 32];

    const int t    = threadIdx.x;
    const int lane = t & 63;
    const int w    = t >> 6;
    const int wy   = w >> 1, wx = w & 1;
    const int rowBase = blockIdx.y * 128;
    const int colBase = blockIdx.x * 128;

    // staging: thread t loads row (r*64 + t>>2), k-chunk (t&3)*8
    const int sm0 = t >> 2;
    const int kch = (t & 3) * 8;

    const ushort_t *a0i, *a0j = nullptr, *a1i, *a1j = nullptr;
    if (GATHER) {
        const int e0 = rowBase + sm0, e1 = rowBase + 64 + sm0;
        a0i = A + ((size_t)(pb[e0] * Nc + pi[e0])) * Dc;
        a0j = A + ((size_t)(pb[e0] * Nc + pj[e0])) * Dc;
        a1i = A + ((size_t)(pb[e1] * Nc + pi[e1])) * Dc;
        a1j = A + ((size_t)(pb[e1] * Nc + pj[e1])) * Dc;
    } else {
        a0i = A + (size_t)(rowBase + sm0) * K;
        a1i = A + (size_t)(rowBase + 64 + sm0) * K;
    }
    const ushort_t* b0 = Bt + (size_t)(colBase + sm0) * K;
    const ushort_t* b1 = Bt + (size_t)(colBase + 64 + sm0) * K;

    // wave-uniform LDS staging bases (in ushort elements; *16B per lane)
    ushort_t* asd0 = As + (size_t)(w * 64) * 8;
    ushort_t* asd1 = As + (size_t)(256 + w * 64) * 8;
    ushort_t* bsd0 = Bs + (size_t)(w * 64) * 8;
    ushort_t* bsd1 = Bs + (size_t)(256 + w * 64) * 8;

    f32x4 acc[4][4];
    const f32x4 fz = {0.f, 0.f, 0.f, 0.f};
    #pragma unroll
    for (int i = 0; i < 4; ++i)
        #pragma unroll
        for (int j = 0; j < 4; ++j) acc[i][j] = fz;

    const int c16 = lane & 15;
    const int q16 = lane >> 4;

    const int nkb = K >> 5;
    for (int kb = 0; kb < nkb; ++kb) {
        const int k0 = kb << 5;
        __syncthreads();   // previous iteration's LDS reads complete
        const ushort_t *pa0, *pa1;
        if (GATHER) {
            const bool first = (k0 < Dc);
            const int kk = first ? k0 : (k0 - Dc);
            pa0 = (first ? a0i : a0j) + kk + kch;
            pa1 = (first ? a1i : a1j) + kk + kch;
        } else {
            pa0 = a0i + k0 + kch;
            pa1 = a1i + k0 + kch;
        }
        gload16(pa0, asd0);
        gload16(pa1, asd1);
        gload16(b0 + k0 + kch, bsd0);
        gload16(b1 + k0 + kch, bsd1);
        __syncthreads();   // staging visible (vmcnt drained before barrier)

        short8 af[4], bf[4];
        #pragma unroll
        for (int i = 0; i < 4; ++i)
            af[i] = *(const short8*)&As[(size_t)((wy * 64 + i * 16 + c16) * 32 + q16 * 8)];
        #pragma unroll
        for (int j = 0; j < 4; ++j)
            bf[j] = *(const short8*)&Bs[(size_t)((wx * 64 + j * 16 + c16) * 32 + q16 * 8)];
        #pragma unroll
        for (int i = 0; i < 4; ++i)
            #pragma unroll
            for (int j = 0; j < 4; ++j)
                acc[i][j] = __builtin_amdgcn_mfma_f32_16x16x32_bf16(af[i], bf[j], acc[i][j], 0, 0, 0);
    }

    // Epilogue: C/D layout col=lane&15, row=(lane>>4)*4+reg  [m89-verified]
    #pragma unroll
    for (int j = 0; j < 4; ++j) {
        const int col = colBase + wx * 64 + j * 16 + c16;
        const float bv = bias[col];
        #pragma unroll
        for (int i = 0; i < 4; ++i) {
            const int row0 = rowBase + wy * 64 + i * 16 + q16 * 4;
            #pragma unroll
            for (int r = 0; r < 4; ++r) {
                float v = acc[i][j][r] + bv;
                if (ACT) v = splus_m_ln2(v);
                const size_t idx = (size_t)(row0 + r) * NOUT + col;
                if (OUTMODE == 1) {
                    ((ushort_t*)Cout)[idx] = f2bf(v);
                } else {
                    ((float*)Cout)[idx] = v;
                    if (OUTMODE == 2) Cout2[idx] = f2bf(v);
                }
            }
        }
    }
}

// ---------------------------------------------------------------------------
// Conversion helpers
// ---------------------------------------------------------------------------
__global__ __launch_bounds__(256) void cvt_f32_bf16(
    const float* __restrict__ src, ushort_t* __restrict__ dst)
{
    const int i = blockIdx.x * 256 + threadIdx.x;
    float4 v = ((const float4*)src)[i];
    ushort4 o;
    o.x = f2bf(v.x); o.y = f2bf(v.y); o.z = f2bf(v.z); o.w = f2bf(v.w);
    ((ushort4*)dst)[i] = o;
}

// Wt[n][k] = bf16(W[k][n]); block (32,8), one 32x32 tile per block
__global__ void transpose_cvt(const float* __restrict__ W, ushort_t* __restrict__ Wt,
                              int K, int NOUT)
{
    __shared__ float tile[32][33];
    const int k0 = blockIdx.x * 32, n0 = blockIdx.y * 32;
    #pragma unroll
    for (int r = 0; r < 4; ++r)
        tile[threadIdx.y + r * 8][threadIdx.x] =
            W[(size_t)(k0 + threadIdx.y + r * 8) * NOUT + n0 + threadIdx.x];
    __syncthreads();
    #pragma unroll
    for (int r = 0; r < 4; ++r)
        Wt[(size_t)(n0 + threadIdx.y + r * 8) * K + k0 + threadIdx.x] =
            f2bf(tile[threadIdx.x][threadIdx.y + r * 8]);
}

// ---------------------------------------------------------------------------
// Global attention, tiled (fp32):
// block = 256 threads, one (b, h, 16-row q-tile).  grid = (N/16, B*HH).
// K streamed through LDS in 4 chunks of 128 rows (stride 36 pad), full score
// row S[16][512] (stride 516 pad) in LDS, 2-pass softmax per 16-lane row
// group, then V streamed through the same LDS chunk buffer for PV.
// LDS = (8256 + 4608 + 576)*4 = 53.8 KB -> 2 blocks/CU.
// ctx layout: ctx[b,n, h*64+0:32]=global head h ; [h*64+32:64]=local head h
// ---------------------------------------------------------------------------
__global__ __launch_bounds__(256) void global_attn(
    const float* __restrict__ qp, const float* __restrict__ kp,
    const float* __restrict__ vp, float* __restrict__ ctx,
    float* __restrict__ top)
{
    __shared__ float S[16 * 516];     // scores, row stride 516 (pad 4)
    __shared__ float KV[128 * 36];    // K or V chunk, row stride 36 (pad 4)
    __shared__ float Qs[16 * 36];     // scaled Q tile

    const int t  = threadIdx.x;
    const int bh = blockIdx.y;
    const int b  = bh >> 3;
    const int h  = bh & (HHc - 1);
    const int q0 = blockIdx.x << 4;   // first q row of tile

    const size_t hb = ((size_t)b * Nc) * Dc + h * DHc;   // head base

    // ---- stage Q tile (pre-scaled) ----
    if (t < 128) {
        const int qr = t >> 3, off = (t & 7) << 2;
        float4 v = *(const float4*)&qp[hb + (size_t)(q0 + qr) * Dc + off];
        float* dst = &Qs[qr * 36 + off];
        dst[0] = v.x * SCALE; dst[1] = v.y * SCALE;
        dst[2] = v.z * SCALE; dst[3] = v.w * SCALE;
    }
    __syncthreads();

    const int q  = t >> 4;    // 0..15  (q row within tile; 16 lanes per row)
    const int lj = t & 15;    // lane within row group

    float qreg[32];
    #pragma unroll
    for (int d4 = 0; d4 < 8; ++d4) {
        float4 v = *(const float4*)&Qs[q * 36 + (d4 << 2)];
        qreg[(d4 << 2) + 0] = v.x; qreg[(d4 << 2) + 1] = v.y;
        qreg[(d4 << 2) + 2] = v.z; qreg[(d4 << 2) + 3] = v.w;
    }

    // ---- phase 1: scores S[q][k] over 4 K-chunks of 128 rows ----
    const int kr  = t >> 1;           // staging row 0..127
    const int koff = (t & 1) << 4;    // staging half-row offset
    for (int c = 0; c < 4; ++c) {
        __syncthreads();   // previous chunk's reads of KV complete
        {
            const float* src = &kp[hb + (size_t)((c << 7) + kr) * Dc + koff];
            float* dst = &KV[kr * 36 + koff];
            *(float4*)&dst[0]  = *(const float4*)&src[0];
            *(float4*)&dst[4]  = *(const float4*)&src[4];
            *(float4*)&dst[8]  = *(const float4*)&src[8];
            *(float4*)&dst[12] = *(const float4*)&src[12];
        }
        __syncthreads();
        #pragma unroll
        for (int i = 0; i < 8; ++i) {
            const int k = lj + (i << 4);
            const float* krow = &KV[k * 36];
            float s0 = 0.f, s1 = 0.f, s2 = 0.f, s3 = 0.f;
            #pragma unroll
            for (int d4 = 0; d4 < 8; ++d4) {
                float4 kv4 = *(const float4*)&krow[d4 << 2];
                s0 += qreg[(d4 << 2) + 0] * kv4.x;
                s1 += qreg[(d4 << 2) + 1] * kv4.y;
                s2 += qreg[(d4 << 2) + 2] * kv4.z;
                s3 += qreg[(d4 << 2) + 3] * kv4.w;
            }
            S[q * 516 + (c << 7) + k] = (s0 + s1) + (s2 + s3);
        }
    }
    __syncthreads();   // all scores visible to all threads

    // ---- top write (h==0): raw scaled scores, before exp overwrites S ----
    if (h == 0) {
        float* trow = top + ((size_t)(b * Nc + q0)) * Nc;   // 16 rows, contiguous
        #pragma unroll
        for (int i = 0; i < 8; ++i) {
            const int f = (i << 8) + t;       // float4 index 0..2047
            const int l = f << 2;             // linear float index
            const int r = l >> 9, k = l & 511;
            *(float4*)&trow[l] = *(const float4*)&S[r * 516 + k];
        }
        __syncthreads();   // top reads done before exp pass overwrites S
    }

    // ---- softmax per row (16 lanes per row, interleaved scan) ----
    const int sbase = q * 516;
    float m = -1e30f;
    #pragma unroll
    for (int i = 0; i < 32; ++i)
        m = fmaxf(m, S[sbase + lj + (i << 4)]);
    #pragma unroll
    for (int off = 1; off < 16; off <<= 1)
        m = fmaxf(m, __shfl_xor(m, off, 64));
    float l = 0.f;
    #pragma unroll
    for (int i = 0; i < 32; ++i) {
        const int idx = sbase + lj + (i << 4);
        const float e = __expf(S[idx] - m);
        S[idx] = e;
        l += e;
    }
    #pragma unroll
    for (int off = 1; off < 16; off <<= 1)
        l += __shfl_xor(l, off, 64);
    const float inv = 1.0f / l;
    // (no barrier needed: S row q is only read below by the 16 lanes that
    //  wrote it — same wave)

    // ---- phase 2: PV over 4 V-chunks; thread owns (q, d-pair) ----
    const int d2 = lj;                // output dims d2*2, d2*2+1
    float a00 = 0.f, a01 = 0.f, a10 = 0.f, a11 = 0.f;
    for (int c = 0; c < 4; ++c) {
        __syncthreads();   // phase-1 (or prev chunk) reads of KV complete
        {
            const float* src = &vp[hb + (size_t)((c << 7) + kr) * Dc + koff];
            float* dst = &KV[kr * 36 + koff];
            *(float4*)&dst[0]  = *(const float4*)&src[0];
            *(float4*)&dst[4]  = *(const float4*)&src[4];
            *(float4*)&dst[8]  = *(const float4*)&src[8];
            *(float4*)&dst[12] = *(const float4*)&src[12];
        }
        __syncthreads();
        const float* srow = &S[sbase + (c << 7)];
        #pragma unroll 8
        for (int k = 0; k < 128; k += 2) {
            const float w0 = srow[k];
            const float w1 = srow[k + 1];
            const float2 v0 = *(const float2*)&KV[k * 36 + (d2 << 1)];
            const float2 v1 = *(const float2*)&KV[(k + 1) * 36 + (d2 << 1)];
            a00 = fmaf(w0, v0.x, a00); a01 = fmaf(w0, v0.y, a01);
            a10 = fmaf(w1, v1.x, a10); a11 = fmaf(w1, v1.y, a11);
        }
    }
    float2 o;
    o.x = (a00 + a10) * inv;
    o.y = (a01 + a11) * inv;
    *(float2*)&ctx[((size_t)(b * Nc + q0 + q)) * Dc + (h << 6) + (d2 << 1)] = o;
}

// ---------------------------------------------------------------------------
// Local attention (ef2 bf16)
// ---------------------------------------------------------------------------
__global__ __launch_bounds__(256) void local_scores(
    const float* __restrict__ qp, const float* __restrict__ kp,
    const ushort_t* __restrict__ ef2,
    const int* __restrict__ pb, const int* __restrict__ pi,
    const int* __restrict__ pj, float* __restrict__ sl)
{
    const int gid = blockIdx.x * 256 + threadIdx.x;   // e*8 + h
    const int h = gid & 7;
    const int e = gid >> 3;
    const int b = pb[e], i = pi[e], j = pj[e];
    const float* qrow = qp  + ((size_t)(b * Nc + i)) * Dc + (HHc + h) * DHc;
    const float* krow = kp  + ((size_t)(b * Nc + j)) * Dc + (HHc + h) * DHc;
    const ushort_t* erow = ef2 + (size_t)e * 256 + h * DHc;
    float s = 0.f;
    #pragma unroll
    for (int d4 = 0; d4 < 8; ++d4) {
        float4 qv = *(const float4*)&qrow[d4 << 2];
        float4 kv = *(const float4*)&krow[d4 << 2];
        ushort4 ev = *(const ushort4*)&erow[d4 << 2];
        s += qv.x * kv.x * bf2f(ev.x) + qv.y * kv.y * bf2f(ev.y)
           + qv.z * kv.z * bf2f(ev.z) + qv.w * kv.w * bf2f(ev.w);
    }
    sl[gid] = s * SCALE;
}

__global__ __launch_bounds__(256) void local_softmax(float* __restrict__ sl)
{
    const int gid = blockIdx.x * 256 + threadIdx.x;   // bi*8 + h
    const int h  = gid & 7;
    const int bi = gid >> 3;
    float s[DEGc];
    float m = -1e30f;
    #pragma unroll
    for (int tt = 0; tt < DEGc; ++tt) {
        s[tt] = sl[(size_t)(bi * DEGc + tt) * 8 + h];
        m = fmaxf(m, s[tt]);
    }
    float l = 0.f;
    #pragma unroll
    for (int tt = 0; tt < DEGc; ++tt) { s[tt] = expf(s[tt] - m); l += s[tt]; }
    const float inv = 1.0f / l;
    #pragma unroll
    for (int tt = 0; tt < DEGc; ++tt)
        sl[(size_t)(bi * DEGc + tt) * 8 + h] = s[tt] * inv;
}

__global__ __launch_bounds__(256) void local_ctx_kernel(
    const float* __restrict__ vp, const float* __restrict__ sl,
    const int* __restrict__ pj, float* __restrict__ ctx)
{
    const int bi = blockIdx.x;            // b*N + i
    const int t  = threadIdx.x;
    const int d  = t & 31;
    const int h  = t >> 5;
    __shared__ float a_s[DEGc][8];
    __shared__ int   jrow[DEGc];
    const int b = bi >> 9;
    if (t < DEGc) jrow[t] = pj[bi * DEGc + t];
    if (t < DEGc * 8) a_s[t >> 3][t & 7] = sl[(size_t)bi * (DEGc * 8) + t];
    __syncthreads();
    float acc = 0.f;
    #pragma unroll
    for (int tt = 0; tt < DEGc; ++tt) {
        const int j = jrow[tt];
        acc += a_s[tt][h] * vp[((size_t)(b * Nc + j)) * Dc + (HHc + h) * DHc + d];
    }
    ctx[(size_t)bi * Dc + (h << 6) + 32 + d] = acc;
}

// ---------------------------------------------------------------------------
extern "C" void kernel_launch(void* const* d_in, const int* in_sizes, int n_in,
                              void* d_out, int out_size, void* d_ws, size_t ws_size,
                              hipStream_t stream) {
    const float* key   = (const float*)d_in[0];
    const float* value = (const float*)d_in[1];
    const float* query = (const float*)d_in[2];
    const float* edge_feature = (const float*)d_in[4];
    const int* pb = (const int*)d_in[5];
    const int* pi = (const int*)d_in[6];
    const int* pj = (const int*)d_in[7];
    const float* Wq = (const float*)d_in[8];  const float* bq = (const float*)d_in[9];
    const float* Wk = (const float*)d_in[10]; const float* bk = (const float*)d_in[11];
    const float* Wv = (const float*)d_in[12]; const float* bv = (const float*)d_in[13];
    const float* Wo = (const float*)d_in[14]; const float* bo = (const float*)d_in[15];
    const float* We1 = (const float*)d_in[16]; const float* be1 = (const float*)d_in[17];
    const float* We2 = (const float*)d_in[18]; const float* be2 = (const float*)d_in[19];
    const float* Wu1 = (const float*)d_in[20]; const float* bu1 = (const float*)d_in[21];
    const float* Wu2 = (const float*)d_in[22]; const float* bu2 = (const float*)d_in[23];

    float* out  = (float*)d_out;          // (B,N,D)
    float* top  = out + 2097152;          // (B,N,N)
    float* eupd = out + 4194304;          // (E,D)

    float* qp  = (float*)d_ws;            // 2097152 f
    float* kp  = qp + 2097152;
    float* vp  = kp + 2097152;
    float* ctx = vp + 2097152;
    float* sl  = ctx + 2097152;           // 524288 f
    ushort_t* ef2b  = (ushort_t*)(sl + 524288);   // E*256
    ushort_t* efb   = ef2b + 16777216;            // E*512
    ushort_t* hidb  = efb + 33554432;             // E*512
    ushort_t* outb  = hidb + 33554432;            // 2097152
    ushort_t* wt_e1 = outb + 2097152;             // 512*512
    ushort_t* wt_e2 = wt_e1 + 262144;             // 256*512
    ushort_t* wt_u1 = wt_e2 + 131072;             // 512*1024
    ushort_t* wt_u2 = wt_u1 + 524288;             // 512*512

    // Aliased into efb's region — efb is dead after the first edge-MLP GEMM,
    // and the edge path is launched FIRST (stream-serialized), so no overlap.
    ushort_t* wt_q = efb;                 // 262144
    ushort_t* wt_k = wt_q + 262144;
    ushort_t* wt_v = wt_k + 262144;
    ushort_t* wt_o = wt_v + 262144;
    ushort_t* qb   = wt_o + 262144;       // 2097152
    ushort_t* kb   = qb + 2097152;
    ushort_t* vb   = kb + 2097152;
    ushort_t* ctxb = vb + 2097152;        // ends at efb+9437184 < 33554432 ok

    dim3 blk(256);
    dim3 tblk(32, 8);

    // ---- Edge path first (frees efb for aliasing) ----
    transpose_cvt<<<dim3(16, 16), tblk, 0, stream>>>(We1, wt_e1, 512, 512);
    transpose_cvt<<<dim3(16, 8),  tblk, 0, stream>>>(We2, wt_e2, 512, 256);
    transpose_cvt<<<dim3(32, 16), tblk, 0, stream>>>(Wu1, wt_u1, 1024, 512);
    transpose_cvt<<<dim3(16, 16), tblk, 0, stream>>>(Wu2, wt_u2, 512, 512);
    cvt_f32_bf16<<<32768, blk, 0, stream>>>(edge_feature, efb);

    // Edge MLP (bf16 MFMA): hid = act(ef @ We1 + be1); ef2 = hid @ We2 + be2
    gemm_mfma<1, 0, 1><<<dim3(4, 512), blk, 0, stream>>>(efb, wt_e1, be1, hidb, nullptr, 512, 512, nullptr, nullptr, nullptr);
    gemm_mfma<0, 0, 1><<<dim3(2, 512), blk, 0, stream>>>(hidb, wt_e2, be2, ef2b, nullptr, 512, 256, nullptr, nullptr, nullptr);
    // efb dead from here on.

    // ---- QKV projections on the matrix pipe ----
    transpose_cvt<<<dim3(16, 16), tblk, 0, stream>>>(Wq, wt_q, 512, 512);
    transpose_cvt<<<dim3(16, 16), tblk, 0, stream>>>(Wk, wt_k, 512, 512);
    transpose_cvt<<<dim3(16, 16), tblk, 0, stream>>>(Wv, wt_v, 512, 512);
    transpose_cvt<<<dim3(16, 16), tblk, 0, stream>>>(Wo, wt_o, 512, 512);
    cvt_f32_bf16<<<2048, blk, 0, stream>>>(query, qb);
    cvt_f32_bf16<<<2048, blk, 0, stream>>>(key,   kb);
    cvt_f32_bf16<<<2048, blk, 0, stream>>>(value, vb);

    gemm_mfma<0, 0, 0><<<dim3(4, 32), blk, 0, stream>>>(qb, wt_q, bq, qp, nullptr, 512, 512, nullptr, nullptr, nullptr);
    gemm_mfma<0, 0, 0><<<dim3(4, 32), blk, 0, stream>>>(kb, wt_k, bk, kp, nullptr, 512, 512, nullptr, nullptr, nullptr);
    gemm_mfma<0, 0, 0><<<dim3(4, 32), blk, 0, stream>>>(vb, wt_v, bv, vp, nullptr, 512, 512, nullptr, nullptr, nullptr);

    // ---- Attention ----
    global_attn<<<dim3(32, 64), blk, 0, stream>>>(qp, kp, vp, ctx, top);
    local_scores<<<2048, blk, 0, stream>>>(qp, kp, ef2b, pb, pi, pj, sl);
    local_softmax<<<128, blk, 0, stream>>>(sl);
    local_ctx_kernel<<<4096, blk, 0, stream>>>(vp, sl, pj, ctx);

    // ---- Output projection (bf16 MFMA, writes fp32 out + bf16 outb) ----
    cvt_f32_bf16<<<2048, blk, 0, stream>>>(ctx, ctxb);
    gemm_mfma<0, 0, 2><<<dim3(4, 32), blk, 0, stream>>>(ctxb, wt_o, bo, out, outb, 512, 512, nullptr, nullptr, nullptr);

    // ---- Edge update MLP (bf16 MFMA, A gathered from outb, K=1024) ----
    gemm_mfma<1, 1, 1><<<dim3(4, 512), blk, 0, stream>>>(outb, wt_u1, bu1, hidb, nullptr, 1024, 512, pb, pi, pj);
    gemm_mfma<0, 0, 0><<<dim3(4, 512), blk, 0, stream>>>(hidb, wt_u2, bu2, eupd, nullptr, 512, 512, nullptr, nullptr, nullptr);
}

// Round 4
// 748.070 us; speedup vs baseline: 1.5386x; 1.1854x over previous
//
#include <hip/hip_runtime.h>
#include <math.h>

// Problem constants (fixed by reference)
constexpr int Bc   = 8;
constexpr int Nc   = 512;
constexpr int Dc   = 512;
constexpr int HHc  = 8;     // half the heads
constexpr int DHc  = 32;
constexpr int DEGc = 16;
constexpr int Ec   = Bc * Nc * DEGc;          // 65536 edges
constexpr float LN2   = 0.69314718055994530942f;
constexpr float SCALE = 0.17677669529663688110f;  // 1/sqrt(32)

typedef unsigned short ushort_t;
typedef __attribute__((ext_vector_type(8))) short short8;
typedef __attribute__((ext_vector_type(4))) float f32x4;

// softplus(x)-ln2 via native v_exp_f32/v_log_f32 (~7 VALU inst vs ~22 for
// libm log1pf+expf; rel err ~2^-21 << bf16 quantum)
__device__ __forceinline__ float splus_m_ln2(float x) {
    float t = __expf(-fabsf(x));
    return fmaxf(x, 0.0f) + __logf(1.0f + t) - LN2;
}

__device__ __forceinline__ ushort_t f2bf(float x) {
    union { float f; unsigned int u; } v; v.f = x;
    unsigned int r = (v.u + 0x7fffu + ((v.u >> 16) & 1u)) >> 16;   // RNE
    return (ushort_t)r;
}
__device__ __forceinline__ float bf2f(ushort_t x) {
    union { unsigned int u; float f; } v; v.u = ((unsigned int)x) << 16;
    return v.f;
}

__device__ __forceinline__ void gload16(const ushort_t* g, ushort_t* l) {
    __builtin_amdgcn_global_load_lds(
        (const __attribute__((address_space(1))) void*)g,
        (__attribute__((address_space(3))) void*)l, 16, 0, 0);
}

// ---------------------------------------------------------------------------
// bf16 MFMA GEMM (m97 structure): C[M,NOUT] = act(A[M,K] @ Bt^T + bias)
// A: bf16 [M][K] row-major (or GATHER: rows = concat(out[b,i], out[b,j]))
// Bt: bf16 [NOUT][K] (pre-transposed weight)
// OUTMODE: 0 = fp32 out, 1 = bf16 out, 2 = fp32 out + bf16 copy to Cout2
// K, NOUT compile-time: GATHER loop splits into two select-free halves,
// epilogue addressing strength-reduced.
// 128x128 block tile, BK=32, 256 threads = 4 waves in 2x2, 4x4 MFMA frags/wave.
// LDS layout [row][32] bf16 unpadded — required by global_load_lds lane order.
// ---------------------------------------------------------------------------
template<int ACT, int GATHER, int OUTMODE, int K, int NOUT>
__global__ __launch_bounds__(256) void gemm_mfma(
    const ushort_t* __restrict__ A, const ushort_t* __restrict__ Bt,
    const float* __restrict__ bias, void* __restrict__ Cout,
    ushort_t* __restrict__ Cout2,
    const int* __restrict__ pb, const int* __restrict__ pi,
    const int* __restrict__ pj)
{
    __shared__ ushort_t As[128 * 32];
    __shared__ ushort_t Bs[128 * 32];

    const int t    = threadIdx.x;
    const int lane = t & 63;
    const int w    = t >> 6;
    const int wy   = w >> 1, wx = w & 1;
    const int rowBase = blockIdx.y * 128;
    const int colBase = blockIdx.x * 128;

    // staging: thread t loads row (r*64 + t>>2), k-chunk (t&3)*8
    const int sm0 = t >> 2;
    const int kch = (t & 3) * 8;

    const ushort_t *a0i, *a0j = nullptr, *a1i, *a1j = nullptr;
    if (GATHER) {
        const int e0 = rowBase + sm0, e1 = rowBase + 64 + sm0;
        a0i = A + ((size_t)(pb[e0] * Nc + pi[e0])) * Dc;
        a0j = A + ((size_t)(pb[e0] * Nc + pj[e0])) * Dc;
        a1i = A + ((size_t)(pb[e1] * Nc + pi[e1])) * Dc;
        a1j = A + ((size_t)(pb[e1] * Nc + pj[e1])) * Dc;
    } else {
        a0i = A + (size_t)(rowBase + sm0) * K;
        a1i = A + (size_t)(rowBase + 64 + sm0) * K;
    }
    const ushort_t* b0 = Bt + (size_t)(colBase + sm0) * K;
    const ushort_t* b1 = Bt + (size_t)(colBase + 64 + sm0) * K;

    // wave-uniform LDS staging bases (in ushort elements; *16B per lane)
    ushort_t* asd0 = As + (size_t)(w * 64) * 8;
    ushort_t* asd1 = As + (size_t)(256 + w * 64) * 8;
    ushort_t* bsd0 = Bs + (size_t)(w * 64) * 8;
    ushort_t* bsd1 = Bs + (size_t)(256 + w * 64) * 8;

    f32x4 acc[4][4];
    const f32x4 fz = {0.f, 0.f, 0.f, 0.f};
    #pragma unroll
    for (int i = 0; i < 4; ++i)
        #pragma unroll
        for (int j = 0; j < 4; ++j) acc[i][j] = fz;

    const int c16 = lane & 15;
    const int q16 = lane >> 4;

    auto kstep = [&](const ushort_t* pa0, const ushort_t* pa1, int k0) {
        __syncthreads();   // previous iteration's LDS reads complete
        gload16(pa0 + kch, asd0);
        gload16(pa1 + kch, asd1);
        gload16(b0 + k0 + kch, bsd0);
        gload16(b1 + k0 + kch, bsd1);
        __syncthreads();   // staging visible (vmcnt drained before barrier)

        short8 af[4], bf[4];
        #pragma unroll
        for (int i = 0; i < 4; ++i)
            af[i] = *(const short8*)&As[(size_t)((wy * 64 + i * 16 + c16) * 32 + q16 * 8)];
        #pragma unroll
        for (int j = 0; j < 4; ++j)
            bf[j] = *(const short8*)&Bs[(size_t)((wx * 64 + j * 16 + c16) * 32 + q16 * 8)];
        #pragma unroll
        for (int i = 0; i < 4; ++i)
            #pragma unroll
            for (int j = 0; j < 4; ++j)
                acc[i][j] = __builtin_amdgcn_mfma_f32_16x16x32_bf16(af[i], bf[j], acc[i][j], 0, 0, 0);
    };

    if constexpr (GATHER) {
        // first Dc columns come from row i, remaining K-Dc from row j
        for (int kb = 0; kb < (Dc >> 5); ++kb)
            kstep(a0i + (kb << 5), a1i + (kb << 5), kb << 5);
        for (int kb = 0; kb < ((K - Dc) >> 5); ++kb)
            kstep(a0j + (kb << 5), a1j + (kb << 5), Dc + (kb << 5));
    } else {
        for (int kb = 0; kb < (K >> 5); ++kb)
            kstep(a0i + (kb << 5), a1i + (kb << 5), kb << 5);
    }

    // Epilogue: C/D layout col=lane&15, row=(lane>>4)*4+reg  [m89-verified]
    #pragma unroll
    for (int j = 0; j < 4; ++j) {
        const int col = colBase + wx * 64 + j * 16 + c16;
        const float bv = bias[col];
        #pragma unroll
        for (int i = 0; i < 4; ++i) {
            const int row0 = rowBase + wy * 64 + i * 16 + q16 * 4;
            #pragma unroll
            for (int r = 0; r < 4; ++r) {
                float v = acc[i][j][r] + bv;
                if (ACT) v = splus_m_ln2(v);
                const size_t idx = (size_t)(row0 + r) * NOUT + col;
                if (OUTMODE == 1) {
                    ((ushort_t*)Cout)[idx] = f2bf(v);
                } else {
                    ((float*)Cout)[idx] = v;
                    if (OUTMODE == 2) Cout2[idx] = f2bf(v);
                }
            }
        }
    }
}

// ---------------------------------------------------------------------------
// Conversion helpers
// ---------------------------------------------------------------------------
__global__ __launch_bounds__(256) void cvt_f32_bf16(
    const float* __restrict__ src, ushort_t* __restrict__ dst)
{
    const int i = blockIdx.x * 256 + threadIdx.x;
    float4 v = ((const float4*)src)[i];
    ushort4 o;
    o.x = f2bf(v.x); o.y = f2bf(v.y); o.z = f2bf(v.z); o.w = f2bf(v.w);
    ((ushort4*)dst)[i] = o;
}

// Wt[n][k] = bf16(W[k][n]); block (32,8), one 32x32 tile per block
__global__ void transpose_cvt(const float* __restrict__ W, ushort_t* __restrict__ Wt,
                              int K, int NOUT)
{
    __shared__ float tile[32][33];
    const int k0 = blockIdx.x * 32, n0 = blockIdx.y * 32;
    #pragma unroll
    for (int r = 0; r < 4; ++r)
        tile[threadIdx.y + r * 8][threadIdx.x] =
            W[(size_t)(k0 + threadIdx.y + r * 8) * NOUT + n0 + threadIdx.x];
    __syncthreads();
    #pragma unroll
    for (int r = 0; r < 4; ++r)
        Wt[(size_t)(n0 + threadIdx.y + r * 8) * K + k0 + threadIdx.x] =
            f2bf(tile[threadIdx.x][threadIdx.y + r * 8]);
}

// ---------------------------------------------------------------------------
// Global attention, tiled (fp32):
// block = 256 threads, one (b, h, 16-row q-tile).  grid = (N/16, B*HH).
// K streamed through LDS in 4 chunks of 128 rows (stride 36 pad), full score
// row S[16][512] (stride 516 pad) in LDS, 2-pass softmax per 16-lane row
// group, then V streamed through the same LDS chunk buffer for PV.
// LDS = (8256 + 4608 + 576)*4 = 53.8 KB -> 2 blocks/CU.
// ctx layout: ctx[b,n, h*64+0:32]=global head h ; [h*64+32:64]=local head h
// ---------------------------------------------------------------------------
__global__ __launch_bounds__(256) void global_attn(
    const float* __restrict__ qp, const float* __restrict__ kp,
    const float* __restrict__ vp, float* __restrict__ ctx,
    float* __restrict__ top)
{
    __shared__ float S[16 * 516];     // scores, row stride 516 (pad 4)
    __shared__ float KV[128 * 36];    // K or V chunk, row stride 36 (pad 4)
    __shared__ float Qs[16 * 36];     // scaled Q tile

    const int t  = threadIdx.x;
    const int bh = blockIdx.y;
    const int b  = bh >> 3;
    const int h  = bh & (HHc - 1);
    const int q0 = blockIdx.x << 4;   // first q row of tile

    const size_t hb = ((size_t)b * Nc) * Dc + h * DHc;   // head base

    // ---- stage Q tile (pre-scaled) ----
    if (t < 128) {
        const int qr = t >> 3, off = (t & 7) << 2;
        float4 v = *(const float4*)&qp[hb + (size_t)(q0 + qr) * Dc + off];
        float* dst = &Qs[qr * 36 + off];
        dst[0] = v.x * SCALE; dst[1] = v.y * SCALE;
        dst[2] = v.z * SCALE; dst[3] = v.w * SCALE;
    }
    __syncthreads();

    const int q  = t >> 4;    // 0..15  (q row within tile; 16 lanes per row)
    const int lj = t & 15;    // lane within row group

    float qreg[32];
    #pragma unroll
    for (int d4 = 0; d4 < 8; ++d4) {
        float4 v = *(const float4*)&Qs[q * 36 + (d4 << 2)];
        qreg[(d4 << 2) + 0] = v.x; qreg[(d4 << 2) + 1] = v.y;
        qreg[(d4 << 2) + 2] = v.z; qreg[(d4 << 2) + 3] = v.w;
    }

    // ---- phase 1: scores S[q][k] over 4 K-chunks of 128 rows ----
    const int kr  = t >> 1;           // staging row 0..127
    const int koff = (t & 1) << 4;    // staging half-row offset
    for (int c = 0; c < 4; ++c) {
        __syncthreads();   // previous chunk's reads of KV complete
        {
            const float* src = &kp[hb + (size_t)((c << 7) + kr) * Dc + koff];
            float* dst = &KV[kr * 36 + koff];
            *(float4*)&dst[0]  = *(const float4*)&src[0];
            *(float4*)&dst[4]  = *(const float4*)&src[4];
            *(float4*)&dst[8]  = *(const float4*)&src[8];
            *(float4*)&dst[12] = *(const float4*)&src[12];
        }
        __syncthreads();
        #pragma unroll
        for (int i = 0; i < 8; ++i) {
            const int k = lj + (i << 4);
            const float* krow = &KV[k * 36];
            float s0 = 0.f, s1 = 0.f, s2 = 0.f, s3 = 0.f;
            #pragma unroll
            for (int d4 = 0; d4 < 8; ++d4) {
                float4 kv4 = *(const float4*)&krow[d4 << 2];
                s0 += qreg[(d4 << 2) + 0] * kv4.x;
                s1 += qreg[(d4 << 2) + 1] * kv4.y;
                s2 += qreg[(d4 << 2) + 2] * kv4.z;
                s3 += qreg[(d4 << 2) + 3] * kv4.w;
            }
            S[q * 516 + (c << 7) + k] = (s0 + s1) + (s2 + s3);
        }
    }
    __syncthreads();   // all scores visible to all threads

    // ---- top write (h==0): raw scaled scores, before exp overwrites S ----
    if (h == 0) {
        float* trow = top + ((size_t)(b * Nc + q0)) * Nc;   // 16 rows, contiguous
        #pragma unroll
        for (int i = 0; i < 8; ++i) {
            const int f = (i << 8) + t;       // float4 index 0..2047
            const int l = f << 2;             // linear float index
            const int r = l >> 9, k = l & 511;
            *(float4*)&trow[l] = *(const float4*)&S[r * 516 + k];
        }
        __syncthreads();   // top reads done before exp pass overwrites S
    }

    // ---- softmax per row (16 lanes per row, interleaved scan) ----
    const int sbase = q * 516;
    float m = -1e30f;
    #pragma unroll
    for (int i = 0; i < 32; ++i)
        m = fmaxf(m, S[sbase + lj + (i << 4)]);
    #pragma unroll
    for (int off = 1; off < 16; off <<= 1)
        m = fmaxf(m, __shfl_xor(m, off, 64));
    float l = 0.f;
    #pragma unroll
    for (int i = 0; i < 32; ++i) {
        const int idx = sbase + lj + (i << 4);
        const float e = __expf(S[idx] - m);
        S[idx] = e;
        l += e;
    }
    #pragma unroll
    for (int off = 1; off < 16; off <<= 1)
        l += __shfl_xor(l, off, 64);
    const float inv = 1.0f / l;
    // (no barrier needed: S row q is only read below by the 16 lanes that
    //  wrote it — same wave)

    // ---- phase 2: PV over 4 V-chunks; thread owns (q, d-pair) ----
    const int d2 = lj;                // output dims d2*2, d2*2+1
    float a00 = 0.f, a01 = 0.f, a10 = 0.f, a11 = 0.f;
    for (int c = 0; c < 4; ++c) {
        __syncthreads();   // phase-1 (or prev chunk) reads of KV complete
        {
            const float* src = &vp[hb + (size_t)((c << 7) + kr) * Dc + koff];
            float* dst = &KV[kr * 36 + koff];
            *(float4*)&dst[0]  = *(const float4*)&src[0];
            *(float4*)&dst[4]  = *(const float4*)&src[4];
            *(float4*)&dst[8]  = *(const float4*)&src[8];
            *(float4*)&dst[12] = *(const float4*)&src[12];
        }
        __syncthreads();
        const float* srow = &S[sbase + (c << 7)];
        #pragma unroll 8
        for (int k = 0; k < 128; k += 2) {
            const float w0 = srow[k];
            const float w1 = srow[k + 1];
            const float2 v0 = *(const float2*)&KV[k * 36 + (d2 << 1)];
            const float2 v1 = *(const float2*)&KV[(k + 1) * 36 + (d2 << 1)];
            a00 = fmaf(w0, v0.x, a00); a01 = fmaf(w0, v0.y, a01);
            a10 = fmaf(w1, v1.x, a10); a11 = fmaf(w1, v1.y, a11);
        }
    }
    float2 o;
    o.x = (a00 + a10) * inv;
    o.y = (a01 + a11) * inv;
    *(float2*)&ctx[((size_t)(b * Nc + q0 + q)) * Dc + (h << 6) + (d2 << 1)] = o;
}

// ---------------------------------------------------------------------------
// Local attention (ef2 bf16)
// ---------------------------------------------------------------------------
__global__ __launch_bounds__(256) void local_scores(
    const float* __restrict__ qp, const float* __restrict__ kp,
    const ushort_t* __restrict__ ef2,
    const int* __restrict__ pb, const int* __restrict__ pi,
    const int* __restrict__ pj, float* __restrict__ sl)
{
    const int gid = blockIdx.x * 256 + threadIdx.x;   // e*8 + h
    const int h = gid & 7;
    const int e = gid >> 3;
    const int b = pb[e], i = pi[e], j = pj[e];
    const float* qrow = qp  + ((size_t)(b * Nc + i)) * Dc + (HHc + h) * DHc;
    const float* krow = kp  + ((size_t)(b * Nc + j)) * Dc + (HHc + h) * DHc;
    const ushort_t* erow = ef2 + (size_t)e * 256 + h * DHc;
    float s = 0.f;
    #pragma unroll
    for (int d4 = 0; d4 < 8; ++d4) {
        float4 qv = *(const float4*)&qrow[d4 << 2];
        float4 kv = *(const float4*)&krow[d4 << 2];
        ushort4 ev = *(const ushort4*)&erow[d4 << 2];
        s += qv.x * kv.x * bf2f(ev.x) + qv.y * kv.y * bf2f(ev.y)
           + qv.z * kv.z * bf2f(ev.z) + qv.w * kv.w * bf2f(ev.w);
    }
    sl[gid] = s * SCALE;
}

__global__ __launch_bounds__(256) void local_softmax(float* __restrict__ sl)
{
    const int gid = blockIdx.x * 256 + threadIdx.x;   // bi*8 + h
    const int h  = gid & 7;
    const int bi = gid >> 3;
    float s[DEGc];
    float m = -1e30f;
    #pragma unroll
    for (int tt = 0; tt < DEGc; ++tt) {
        s[tt] = sl[(size_t)(bi * DEGc + tt) * 8 + h];
        m = fmaxf(m, s[tt]);
    }
    float l = 0.f;
    #pragma unroll
    for (int tt = 0; tt < DEGc; ++tt) { s[tt] = expf(s[tt] - m); l += s[tt]; }
    const float inv = 1.0f / l;
    #pragma unroll
    for (int tt = 0; tt < DEGc; ++tt)
        sl[(size_t)(bi * DEGc + tt) * 8 + h] = s[tt] * inv;
}

__global__ __launch_bounds__(256) void local_ctx_kernel(
    const float* __restrict__ vp, const float* __restrict__ sl,
    const int* __restrict__ pj, float* __restrict__ ctx)
{
    const int bi = blockIdx.x;            // b*N + i
    const int t  = threadIdx.x;
    const int d  = t & 31;
    const int h  = t >> 5;
    __shared__ float a_s[DEGc][8];
    __shared__ int   jrow[DEGc];
    const int b = bi >> 9;
    if (t < DEGc) jrow[t] = pj[bi * DEGc + t];
    if (t < DEGc * 8) a_s[t >> 3][t & 7] = sl[(size_t)bi * (DEGc * 8) + t];
    __syncthreads();
    float acc = 0.f;
    #pragma unroll
    for (int tt = 0; tt < DEGc; ++tt) {
        const int j = jrow[tt];
        acc += a_s[tt][h] * vp[((size_t)(b * Nc + j)) * Dc + (HHc + h) * DHc + d];
    }
    ctx[(size_t)bi * Dc + (h << 6) + 32 + d] = acc;
}

// ---------------------------------------------------------------------------
extern "C" void kernel_launch(void* const* d_in, const int* in_sizes, int n_in,
                              void* d_out, int out_size, void* d_ws, size_t ws_size,
                              hipStream_t stream) {
    const float* key   = (const float*)d_in[0];
    const float* value = (const float*)d_in[1];
    const float* query = (const float*)d_in[2];
    const float* edge_feature = (const float*)d_in[4];
    const int* pb = (const int*)d_in[5];
    const int* pi = (const int*)d_in[6];
    const int* pj = (const int*)d_in[7];
    const float* Wq = (const float*)d_in[8];  const float* bq = (const float*)d_in[9];
    const float* Wk = (const float*)d_in[10]; const float* bk = (const float*)d_in[11];
    const float* Wv = (const float*)d_in[12]; const float* bv = (const float*)d_in[13];
    const float* Wo = (const float*)d_in[14]; const float* bo = (const float*)d_in[15];
    const float* We1 = (const float*)d_in[16]; const float* be1 = (const float*)d_in[17];
    const float* We2 = (const float*)d_in[18]; const float* be2 = (const float*)d_in[19];
    const float* Wu1 = (const float*)d_in[20]; const float* bu1 = (const float*)d_in[21];
    const float* Wu2 = (const float*)d_in[22]; const float* bu2 = (const float*)d_in[23];

    float* out  = (float*)d_out;          // (B,N,D)
    float* top  = out + 2097152;          // (B,N,N)
    float* eupd = out + 4194304;          // (E,D)

    float* qp  = (float*)d_ws;            // 2097152 f
    float* kp  = qp + 2097152;
    float* vp  = kp + 2097152;
    float* ctx = vp + 2097152;
    float* sl  = ctx + 2097152;           // 524288 f
    ushort_t* ef2b  = (ushort_t*)(sl + 524288);   // E*256
    ushort_t* efb   = ef2b + 16777216;            // E*512
    ushort_t* hidb  = efb + 33554432;             // E*512
    ushort_t* outb  = hidb + 33554432;            // 2097152
    ushort_t* wt_e1 = outb + 2097152;             // 512*512
    ushort_t* wt_e2 = wt_e1 + 262144;             // 256*512
    ushort_t* wt_u1 = wt_e2 + 131072;             // 512*1024
    ushort_t* wt_u2 = wt_u1 + 524288;             // 512*512

    // Aliased into efb's region — efb is dead after the first edge-MLP GEMM,
    // and the edge path is launched FIRST (stream-serialized), so no overlap.
    ushort_t* wt_q = efb;                 // 262144
    ushort_t* wt_k = wt_q + 262144;
    ushort_t* wt_v = wt_k + 262144;
    ushort_t* wt_o = wt_v + 262144;
    ushort_t* qb   = wt_o + 262144;       // 2097152
    ushort_t* kb   = qb + 2097152;
    ushort_t* vb   = kb + 2097152;
    ushort_t* ctxb = vb + 2097152;        // ends at efb+9437184 < 33554432 ok

    dim3 blk(256);
    dim3 tblk(32, 8);

    // ---- Edge path first (frees efb for aliasing) ----
    transpose_cvt<<<dim3(16, 16), tblk, 0, stream>>>(We1, wt_e1, 512, 512);
    transpose_cvt<<<dim3(16, 8),  tblk, 0, stream>>>(We2, wt_e2, 512, 256);
    transpose_cvt<<<dim3(32, 16), tblk, 0, stream>>>(Wu1, wt_u1, 1024, 512);
    transpose_cvt<<<dim3(16, 16), tblk, 0, stream>>>(Wu2, wt_u2, 512, 512);
    cvt_f32_bf16<<<32768, blk, 0, stream>>>(edge_feature, efb);

    // Edge MLP (bf16 MFMA): hid = act(ef @ We1 + be1); ef2 = hid @ We2 + be2
    gemm_mfma<1, 0, 1, 512, 512><<<dim3(4, 512), blk, 0, stream>>>(efb, wt_e1, be1, hidb, nullptr, nullptr, nullptr, nullptr);
    gemm_mfma<0, 0, 1, 512, 256><<<dim3(2, 512), blk, 0, stream>>>(hidb, wt_e2, be2, ef2b, nullptr, nullptr, nullptr, nullptr);
    // efb dead from here on.

    // ---- QKV projections on the matrix pipe ----
    transpose_cvt<<<dim3(16, 16), tblk, 0, stream>>>(Wq, wt_q, 512, 512);
    transpose_cvt<<<dim3(16, 16), tblk, 0, stream>>>(Wk, wt_k, 512, 512);
    transpose_cvt<<<dim3(16, 16), tblk, 0, stream>>>(Wv, wt_v, 512, 512);
    transpose_cvt<<<dim3(16, 16), tblk, 0, stream>>>(Wo, wt_o, 512, 512);
    cvt_f32_bf16<<<2048, blk, 0, stream>>>(query, qb);
    cvt_f32_bf16<<<2048, blk, 0, stream>>>(key,   kb);
    cvt_f32_bf16<<<2048, blk, 0, stream>>>(value, vb);

    gemm_mfma<0, 0, 0, 512, 512><<<dim3(4, 32), blk, 0, stream>>>(qb, wt_q, bq, qp, nullptr, nullptr, nullptr, nullptr);
    gemm_mfma<0, 0, 0, 512, 512><<<dim3(4, 32), blk, 0, stream>>>(kb, wt_k, bk, kp, nullptr, nullptr, nullptr, nullptr);
    gemm_mfma<0, 0, 0, 512, 512><<<dim3(4, 32), blk, 0, stream>>>(vb, wt_v, bv, vp, nullptr, nullptr, nullptr, nullptr);

    // ---- Attention ----
    global_attn<<<dim3(32, 64), blk, 0, stream>>>(qp, kp, vp, ctx, top);
    local_scores<<<2048, blk, 0, stream>>>(qp, kp, ef2b, pb, pi, pj, sl);
    local_softmax<<<128, blk, 0, stream>>>(sl);
    local_ctx_kernel<<<4096, blk, 0, stream>>>(vp, sl, pj, ctx);

    // ---- Output projection (bf16 MFMA, writes fp32 out + bf16 outb) ----
    cvt_f32_bf16<<<2048, blk, 0, stream>>>(ctx, ctxb);
    gemm_mfma<0, 0, 2, 512, 512><<<dim3(4, 32), blk, 0, stream>>>(ctxb, wt_o, bo, out, outb, nullptr, nullptr, nullptr);

    // ---- Edge update MLP (bf16 MFMA, A gathered from outb, K=1024) ----
    gemm_mfma<1, 1, 1, 1024, 512><<<dim3(4, 512), blk, 0, stream>>>(outb, wt_u1, bu1, hidb, nullptr, pb, pi, pj);
    gemm_mfma<0, 0, 0, 512, 512><<<dim3(4, 512), blk, 0, stream>>>(hidb, wt_u2, bu2, eupd, nullptr, nullptr, nullptr, nullptr);
}